// Round 9
// baseline (670.000 us; speedup 1.0000x reference)
//
#include <hip/hip_runtime.h>

#define D_IN 128
#define D_HID 256
#define D_OUT 128
#define BN_EPS 1e-5f

typedef unsigned short u16;
typedef unsigned int u32;
typedef __attribute__((ext_vector_type(8))) short bf16x8;
typedef __attribute__((ext_vector_type(4))) float f32x4;

__device__ __forceinline__ u16 f2b(float f) {   // fp32 -> bf16 RNE
    u32 u = __float_as_uint(f);
    return (u16)((u + 0x7FFFu + ((u >> 16) & 1u)) >> 16);
}
__device__ __forceinline__ float b2f(u16 h) {
    return __uint_as_float(((u32)h) << 16);
}

// ---------------------------------------------------------------------------
// 0) convert + transpose weights to bf16 [n][k] (one-time, tiny)
// ---------------------------------------------------------------------------
__global__ __launch_bounds__(256) void cvt_w(
    const float* __restrict__ w1, const float* __restrict__ w2,
    u16* __restrict__ w1t, u16* __restrict__ w2t)
{
    int i = blockIdx.x * 256 + threadIdx.x;
    if (i < 32768) {                       // w1t[n][k], n<256,k<128 <- w1[k][n]
        int n = i >> 7, k = i & 127;
        w1t[i] = f2b(w1[k * 256 + n]);
    } else {                               // w2t[n][k], n<128,k<256 <- w2[k][n]
        int j = i - 32768;
        int n = j >> 8, k = j & 255;
        w2t[j] = f2b(w2[k * 128 + n]);
    }
}

// ---------------------------------------------------------------------------
// 1) histogram
// ---------------------------------------------------------------------------
__global__ __launch_bounds__(256) void edge_hist(
    const int* __restrict__ rows, int* __restrict__ cnt, int E)
{
    int e = blockIdx.x * 256 + threadIdx.x;
    if (e < E) atomicAdd(&cnt[rows[e]], 1);
}

// ---------------------------------------------------------------------------
// 2a/2b/2c) device-wide exclusive scan (3 phases)
// ---------------------------------------------------------------------------
__global__ __launch_bounds__(256) void chunk_sums(
    const int* __restrict__ cnt, int* __restrict__ bsum, int N)
{
    __shared__ int red[256];
    const int t = threadIdx.x;
    const int i = blockIdx.x * 256 + t;
    red[t] = (i < N) ? cnt[i] : 0;
    __syncthreads();
#pragma unroll
    for (int off = 128; off > 0; off >>= 1) {
        if (t < off) red[t] += red[t + off];
        __syncthreads();
    }
    if (t == 0) bsum[blockIdx.x] = red[0];
}

__global__ __launch_bounds__(256) void scan_chunks(
    const int* __restrict__ bsum, int* __restrict__ coff, int NB)
{
    __shared__ int s[256];
    const int t = threadIdx.x;
    int c = (t < NB) ? bsum[t] : 0;
    s[t] = c;
    __syncthreads();
#pragma unroll
    for (int off = 1; off < 256; off <<= 1) {
        int x = (t >= off) ? s[t - off] : 0;
        __syncthreads();
        s[t] += x;
        __syncthreads();
    }
    coff[t] = s[t] - c;
}

__global__ __launch_bounds__(256) void scan_write(
    const int* __restrict__ cnt, const int* __restrict__ coff,
    int* __restrict__ rowstart, int* __restrict__ cursor, int N)
{
    __shared__ int s[256];
    const int t = threadIdx.x;
    const int i = blockIdx.x * 256 + t;
    int c = (i < N) ? cnt[i] : 0;
    s[t] = c;
    __syncthreads();
#pragma unroll
    for (int off = 1; off < 256; off <<= 1) {
        int x = (t >= off) ? s[t - off] : 0;
        __syncthreads();
        s[t] += x;
        __syncthreads();
    }
    int pos = coff[blockIdx.x] + s[t] - c;
    if (i < N) {
        rowstart[i] = pos;
        cursor[i] = pos;
    } else if (i == N) {
        rowstart[N] = pos;
    }
}

// ---------------------------------------------------------------------------
// 3) bucket-scatter edges
// ---------------------------------------------------------------------------
__global__ __launch_bounds__(256) void edge_scatter(
    const int* __restrict__ rows, const int* __restrict__ cols,
    const float* __restrict__ vals, int* __restrict__ cursor,
    float2* __restrict__ ecv, int E)
{
    int e = blockIdx.x * 256 + threadIdx.x;
    if (e >= E) return;
    int r = rows[e];
    int pos = atomicAdd(&cursor[r], 1);
    ecv[pos] = make_float2(__int_as_float(cols[e]), vals[e]);
}

// ---------------------------------------------------------------------------
// 4) gather-aggregate: one wave/row, 2 edges in flight; writes x as bf16.
// ---------------------------------------------------------------------------
__global__ __launch_bounds__(256) void spmm_rows(
    const float* __restrict__ v, const int* __restrict__ rowstart,
    const float2* __restrict__ ecv, const float* __restrict__ epsp,
    u16* __restrict__ x, int N)
{
    int wid = (blockIdx.x * 256 + threadIdx.x) >> 6;
    if (wid >= N) return;
    const int lane = threadIdx.x & 63;
    const int half = lane >> 5;
    const int l32 = lane & 31;
    const int s = rowstart[wid], e = rowstart[wid + 1];
    float4 acc = make_float4(0.f, 0.f, 0.f, 0.f);

    for (int base = s; base < e; base += 64) {
        int n = min(64, e - base);
        float2 ev = make_float2(0.f, 0.f);
        if (base + lane < e) ev = ecv[base + lane];
        int mycol = __float_as_int(ev.x);
        int pairs = (n + 1) >> 1;
        for (int k = 0; k < pairs; ++k) {
            int idx = 2 * k + half;
            int col = __shfl(mycol, idx);
            float val = __shfl(ev.y, idx);
            const float4 vv = *reinterpret_cast<const float4*>(
                v + (size_t)col * D_IN + l32 * 4);
            acc.x = fmaf(val, vv.x, acc.x);
            acc.y = fmaf(val, vv.y, acc.y);
            acc.z = fmaf(val, vv.z, acc.z);
            acc.w = fmaf(val, vv.w, acc.w);
        }
    }
    acc.x += __shfl_down(acc.x, 32);
    acc.y += __shfl_down(acc.y, 32);
    acc.z += __shfl_down(acc.z, 32);
    acc.w += __shfl_down(acc.w, 32);
    if (half == 0) {
        const float eps = *epsp;
        const float4 vs = *reinterpret_cast<const float4*>(
            v + (size_t)wid * D_IN + l32 * 4);
        u32 a0 = (u32)f2b(fmaf(eps, vs.x, acc.x)) |
                 ((u32)f2b(fmaf(eps, vs.y, acc.y)) << 16);
        u32 a1 = (u32)f2b(fmaf(eps, vs.z, acc.z)) |
                 ((u32)f2b(fmaf(eps, vs.w, acc.w)) << 16);
        *reinterpret_cast<uint2*>(x + (size_t)wid * D_IN + l32 * 4) =
            make_uint2(a0, a1);
    }
}

// ---------------------------------------------------------------------------
// 5/6) MFMA GEMM: C[M][NSTR] (bf16) = A[M][KT] (bf16) @ Bt[n][k] (bf16)
//      BM=64, BN=128, BK=128, 4 waves, XOR-swizzled LDS, fused col stats.
//      BNA=true: A-staging applies relu(a*f.x+f.y) with f cached in LDS.
// ---------------------------------------------------------------------------
template <int KT, int NSTR, bool BNA>
__global__ __launch_bounds__(256) void gemm_mf(
    const u16* __restrict__ A, const u16* __restrict__ Bt,
    const float2* __restrict__ fA, u16* __restrict__ C,
    float* __restrict__ sum, float* __restrict__ sq, int M)
{
    __shared__ u16 As[64 * 128];    // 16 KB, swizzled
    __shared__ u16 Bs[128 * 128];   // 32 KB, swizzled
    __shared__ float2 fs[256];      // BN factors cache (2 KB)

    const int tid = threadIdx.x;
    const int bm = blockIdx.x * 64;
    const int bn0 = blockIdx.y * 128;
    const int l = tid & 63;
    const int wm = (tid >> 6) * 16;        // wave's 16-row band
    char* AsB = reinterpret_cast<char*>(As);
    char* BsB = reinterpret_cast<char*>(Bs);

    if (BNA) fs[tid] = fA[tid];            // KT==256 when BNA

    f32x4 acc[8];
#pragma unroll
    for (int t = 0; t < 8; ++t) acc[t] = (f32x4){0.f, 0.f, 0.f, 0.f};

    for (int kk = 0; kk < KT; kk += 128) {
        __syncthreads();                   // fs ready / previous pass done
        // ---- stage A tile (64 x 128 bf16), swizzled ----
#pragma unroll
        for (int i = 0; i < 4; ++i) {
            int c = tid + i * 256;
            int row = c >> 4, slot = c & 15;
            uint4 val = make_uint4(0u, 0u, 0u, 0u);
            if (bm + row < M)
                val = *reinterpret_cast<const uint4*>(
                    A + (size_t)(bm + row) * KT + kk + slot * 8);
            if (BNA) {
                u16* hp = reinterpret_cast<u16*>(&val);
#pragma unroll
                for (int j = 0; j < 8; ++j) {
                    float2 f = fs[kk + slot * 8 + j];
                    hp[j] = f2b(fmaxf(fmaf(b2f(hp[j]), f.x, f.y), 0.f));
                }
            }
            *reinterpret_cast<uint4*>(
                AsB + ((row * 256 + slot * 16) ^ ((row & 7) << 4))) = val;
        }
        // ---- stage B tile (128 x 128 bf16), swizzled ----
#pragma unroll
        for (int i = 0; i < 8; ++i) {
            int c = tid + i * 256;
            int n = c >> 4, slot = c & 15;
            uint4 val = *reinterpret_cast<const uint4*>(
                Bt + (size_t)(bn0 + n) * KT + kk + slot * 8);
            *reinterpret_cast<uint4*>(
                BsB + ((n * 256 + slot * 16) ^ ((n & 7) << 4))) = val;
        }
        __syncthreads();
        // ---- MFMA: wave computes 16 rows x 128 cols ----
#pragma unroll
        for (int s = 0; s < 4; ++s) {
            int ka = (s * 32 + (l >> 4) * 8) * 2;      // k byte offset in row
            int arow = wm + (l & 15);
            bf16x8 af = *reinterpret_cast<bf16x8*>(
                AsB + ((arow * 256 + ka) ^ ((l & 7) << 4)));
#pragma unroll
            for (int t = 0; t < 8; ++t) {
                int brow = t * 16 + (l & 15);
                bf16x8 bfr = *reinterpret_cast<bf16x8*>(
                    BsB + ((brow * 256 + ka) ^ ((l & 7) << 4)));
                acc[t] = __builtin_amdgcn_mfma_f32_16x16x32_bf16(
                    af, bfr, acc[t], 0, 0, 0);
            }
        }
    }

    // ---- fused column stats (fp32 acc; padded rows contribute 0) ----
#pragma unroll
    for (int t = 0; t < 8; ++t) {
        float s = acc[t][0] + acc[t][1] + acc[t][2] + acc[t][3];
        float q = acc[t][0] * acc[t][0] + acc[t][1] * acc[t][1]
                + acc[t][2] * acc[t][2] + acc[t][3] * acc[t][3];
        s += __shfl_down(s, 32);  q += __shfl_down(q, 32);
        s += __shfl_down(s, 16);  q += __shfl_down(q, 16);
        if ((l >> 4) == 0) {
            atomicAdd(&sum[bn0 + t * 16 + l], s);
            atomicAdd(&sq[bn0 + t * 16 + l], q);
        }
    }

    // ---- C store: acc -> LDS (bf16, reuse As) -> coalesced global ----
    __syncthreads();
#pragma unroll
    for (int t = 0; t < 8; ++t) {
#pragma unroll
        for (int r = 0; r < 4; ++r) {
            int row = wm + (l >> 4) * 4 + r;
            int col = t * 16 + (l & 15);
            *reinterpret_cast<u16*>(
                AsB + ((row * 256 + col * 2) ^ ((row & 7) << 4))) =
                f2b(acc[t][r]);
        }
    }
    __syncthreads();
#pragma unroll
    for (int i = 0; i < 4; ++i) {
        int c = tid + i * 256;
        int row = c >> 4, slot = c & 15;
        if (bm + row < M) {
            uint4 val = *reinterpret_cast<uint4*>(
                AsB + ((row * 256 + slot * 16) ^ ((row & 7) << 4)));
            *reinterpret_cast<uint4*>(
                C + (size_t)(bm + row) * NSTR + bn0 + slot * 8) = val;
        }
    }
}

// ---------------------------------------------------------------------------
// 7) BN factors: s = g*rsqrt(var+eps); t = be - mean*s  (linear bias cancels)
// ---------------------------------------------------------------------------
__global__ void bnfactors(const float* __restrict__ sum, const float* __restrict__ sq,
                          const float* __restrict__ g, const float* __restrict__ be,
                          float2* __restrict__ f, int C, int M)
{
    int c = threadIdx.x;
    if (c < C) {
        float inv = 1.f / (float)M;
        float mean = sum[c] * inv;
        float var = fmaxf(sq[c] * inv - mean * mean, 0.f);
        float s = g[c] * rsqrtf(var + BN_EPS);
        f[c] = make_float2(s, be[c] - mean * s);
    }
}

// ---------------------------------------------------------------------------
// 8) final elementwise: out = relu(y2*s2 + t2), y2 bf16 -> out fp32
// ---------------------------------------------------------------------------
__global__ __launch_bounds__(256) void bnrelu_out(
    const u16* __restrict__ y2, const float2* __restrict__ f2,
    float* __restrict__ out, int total8)
{
    int i = blockIdx.x * 256 + threadIdx.x;
    if (i >= total8) return;
    uint4 val = *reinterpret_cast<const uint4*>(y2 + (size_t)i * 8);
    const u16* hp = reinterpret_cast<const u16*>(&val);
    int c = (i & 15) * 8;                  // D_OUT=128 -> 16 chunks/row
    float r[8];
#pragma unroll
    for (int j = 0; j < 8; ++j) {
        float2 f = f2[c + j];
        r[j] = fmaxf(fmaf(b2f(hp[j]), f.x, f.y), 0.f);
    }
    *reinterpret_cast<float4*>(out + (size_t)i * 8) =
        make_float4(r[0], r[1], r[2], r[3]);
    *reinterpret_cast<float4*>(out + (size_t)i * 8 + 4) =
        make_float4(r[4], r[5], r[6], r[7]);
}

// ---------------------------------------------------------------------------
extern "C" void kernel_launch(void* const* d_in, const int* in_sizes, int n_in,
                              void* d_out, int out_size, void* d_ws, size_t ws_size,
                              hipStream_t stream)
{
    const float* v     = (const float*)d_in[0];
    const int*   erows = (const int*)d_in[1];
    const int*   ecols = (const int*)d_in[2];
    const float* evals = (const float*)d_in[3];
    const float* w1    = (const float*)d_in[4];
    // b1 = d_in[5], b2 = d_in[9]: linear bias cancels exactly inside BatchNorm.
    const float* g1    = (const float*)d_in[6];
    const float* be1   = (const float*)d_in[7];
    const float* w2    = (const float*)d_in[8];
    const float* g2    = (const float*)d_in[10];
    const float* be2   = (const float*)d_in[11];
    const float* eps   = (const float*)d_in[12];

    const int M = in_sizes[0] / D_IN;   // 50000
    const int E = in_sizes[3];          // 800000
    const int NB = (M + 255) / 256;     // 196 chunks

    u16* xb  = (u16*)d_ws;                           // M*128 bf16
    u16* y1b = xb + (size_t)M * D_IN;                // M*256 bf16
    u16* w1t = y1b + (size_t)M * D_HID;              // 32768
    u16* w2t = w1t + 32768;                          // 32768
    int* rowstart = (int*)(w2t + 32768);             // N+1
    int* cursor   = rowstart + M + 2;
    int* cnthist  = cursor + M;
    int* bsum     = cnthist + M;                     // 256
    int* coff     = bsum + 256;                      // 256
    size_t ecv_ofs = ((size_t)(coff + 256 - (int*)d_ws) + 1) & ~(size_t)1;
    float2* ecv = (float2*)((float*)d_ws + ecv_ofs); // E float2
    float* st   = (float*)(ecv + E);
    float* sum1 = st;
    float* sq1  = sum1 + D_HID;
    float* sum2 = sq1 + D_HID;
    float* sq2  = sum2 + D_OUT;
    float2* f1  = (float2*)(sq2 + D_OUT);            // 256 float2
    float2* f2  = f1 + D_HID;                        // 128 float2
    u16* y2b    = xb;                                // alias: x dead after GEMM1
    float* outp = (float*)d_out;

    hipMemsetAsync(cnthist, 0, (size_t)M * sizeof(int), stream);
    hipMemsetAsync(st, 0, (size_t)(2 * D_HID + 2 * D_OUT) * sizeof(float), stream);

    cvt_w<<<256, 256, 0, stream>>>(w1, w2, w1t, w2t);
    edge_hist<<<(E + 255) / 256, 256, 0, stream>>>(erows, cnthist, E);
    chunk_sums<<<NB, 256, 0, stream>>>(cnthist, bsum, M);
    scan_chunks<<<1, 256, 0, stream>>>(bsum, coff, NB);
    scan_write<<<NB, 256, 0, stream>>>(cnthist, coff, rowstart, cursor, M);
    edge_scatter<<<(E + 255) / 256, 256, 0, stream>>>(erows, ecols, evals, cursor, ecv, E);
    spmm_rows<<<(M * 64 + 255) / 256, 256, 0, stream>>>(v, rowstart, ecv, eps, xb, M);

    dim3 grid1((M + 63) / 64, 2);
    gemm_mf<128, 256, false><<<grid1, 256, 0, stream>>>(
        xb, w1t, nullptr, y1b, sum1, sq1, M);
    bnfactors<<<1, D_HID, 0, stream>>>(sum1, sq1, g1, be1, f1, D_HID, M);

    dim3 grid2((M + 63) / 64, 1);
    gemm_mf<256, 128, true><<<grid2, 256, 0, stream>>>(
        y1b, w2t, f1, y2b, sum2, sq2, M);
    bnfactors<<<1, D_OUT, 0, stream>>>(sum2, sq2, g2, be2, f2, D_OUT, M);

    bnrelu_out<<<(M * D_OUT / 8 + 255) / 256, 256, 0, stream>>>(
        y2b, f2, outp, M * D_OUT / 8);
}

// Round 11
// 340.784 us; speedup vs baseline: 1.9661x; 1.9661x over previous
//
#include <hip/hip_runtime.h>

#define D_IN 128
#define D_HID 256
#define D_OUT 128
#define BN_EPS 1e-5f

typedef unsigned short u16;
typedef unsigned int u32;
typedef __attribute__((ext_vector_type(8))) short bf16x8;
typedef __attribute__((ext_vector_type(4))) float f32x4;

__device__ __forceinline__ u16 f2b(float f) {   // fp32 -> bf16 RNE
    u32 u = __float_as_uint(f);
    return (u16)((u + 0x7FFFu + ((u >> 16) & 1u)) >> 16);
}
__device__ __forceinline__ float b2f(u16 h) {
    return __uint_as_float(((u32)h) << 16);
}

// ---------------------------------------------------------------------------
// 0) convert + transpose weights to bf16 [n][k] (one-time, tiny)
// ---------------------------------------------------------------------------
__global__ __launch_bounds__(256) void cvt_w(
    const float* __restrict__ w1, const float* __restrict__ w2,
    u16* __restrict__ w1t, u16* __restrict__ w2t)
{
    int i = blockIdx.x * 256 + threadIdx.x;
    if (i < 32768) {                       // w1t[n][k], n<256,k<128 <- w1[k][n]
        int n = i >> 7, k = i & 127;
        w1t[i] = f2b(w1[k * 256 + n]);
    } else {                               // w2t[n][k], n<128,k<256 <- w2[k][n]
        int j = i - 32768;
        int n = j >> 8, k = j & 255;
        w2t[j] = f2b(w2[k * 128 + n]);
    }
}

// ---------------------------------------------------------------------------
// 1) histogram
// ---------------------------------------------------------------------------
__global__ __launch_bounds__(256) void edge_hist(
    const int* __restrict__ rows, int* __restrict__ cnt, int E)
{
    int e = blockIdx.x * 256 + threadIdx.x;
    if (e < E) atomicAdd(&cnt[rows[e]], 1);
}

// ---------------------------------------------------------------------------
// 2a/2b/2c) device-wide exclusive scan (3 phases)
// ---------------------------------------------------------------------------
__global__ __launch_bounds__(256) void chunk_sums(
    const int* __restrict__ cnt, int* __restrict__ bsum, int N)
{
    __shared__ int red[256];
    const int t = threadIdx.x;
    const int i = blockIdx.x * 256 + t;
    red[t] = (i < N) ? cnt[i] : 0;
    __syncthreads();
#pragma unroll
    for (int off = 128; off > 0; off >>= 1) {
        if (t < off) red[t] += red[t + off];
        __syncthreads();
    }
    if (t == 0) bsum[blockIdx.x] = red[0];
}

__global__ __launch_bounds__(256) void scan_chunks(
    const int* __restrict__ bsum, int* __restrict__ coff, int NB)
{
    __shared__ int s[256];
    const int t = threadIdx.x;
    int c = (t < NB) ? bsum[t] : 0;
    s[t] = c;
    __syncthreads();
#pragma unroll
    for (int off = 1; off < 256; off <<= 1) {
        int x = (t >= off) ? s[t - off] : 0;
        __syncthreads();
        s[t] += x;
        __syncthreads();
    }
    coff[t] = s[t] - c;
}

__global__ __launch_bounds__(256) void scan_write(
    const int* __restrict__ cnt, const int* __restrict__ coff,
    int* __restrict__ rowstart, int* __restrict__ cursor, int N)
{
    __shared__ int s[256];
    const int t = threadIdx.x;
    const int i = blockIdx.x * 256 + t;
    int c = (i < N) ? cnt[i] : 0;
    s[t] = c;
    __syncthreads();
#pragma unroll
    for (int off = 1; off < 256; off <<= 1) {
        int x = (t >= off) ? s[t - off] : 0;
        __syncthreads();
        s[t] += x;
        __syncthreads();
    }
    int pos = coff[blockIdx.x] + s[t] - c;
    if (i < N) {
        rowstart[i] = pos;
        cursor[i] = pos;
    } else if (i == N) {
        rowstart[N] = pos;
    }
}

// ---------------------------------------------------------------------------
// 3) bucket-scatter edges
// ---------------------------------------------------------------------------
__global__ __launch_bounds__(256) void edge_scatter(
    const int* __restrict__ rows, const int* __restrict__ cols,
    const float* __restrict__ vals, int* __restrict__ cursor,
    float2* __restrict__ ecv, int E)
{
    int e = blockIdx.x * 256 + threadIdx.x;
    if (e >= E) return;
    int r = rows[e];
    int pos = atomicAdd(&cursor[r], 1);
    ecv[pos] = make_float2(__int_as_float(cols[e]), vals[e]);
}

// ---------------------------------------------------------------------------
// 4) gather-aggregate: one wave/row, 2 edges in flight; writes x as bf16.
// ---------------------------------------------------------------------------
__global__ __launch_bounds__(256) void spmm_rows(
    const float* __restrict__ v, const int* __restrict__ rowstart,
    const float2* __restrict__ ecv, const float* __restrict__ epsp,
    u16* __restrict__ x, int N)
{
    int wid = (blockIdx.x * 256 + threadIdx.x) >> 6;
    if (wid >= N) return;
    const int lane = threadIdx.x & 63;
    const int half = lane >> 5;
    const int l32 = lane & 31;
    const int s = rowstart[wid], e = rowstart[wid + 1];
    float4 acc = make_float4(0.f, 0.f, 0.f, 0.f);

    for (int base = s; base < e; base += 64) {
        int n = min(64, e - base);
        float2 ev = make_float2(0.f, 0.f);
        if (base + lane < e) ev = ecv[base + lane];
        int mycol = __float_as_int(ev.x);
        int pairs = (n + 1) >> 1;
        for (int k = 0; k < pairs; ++k) {
            int idx = 2 * k + half;
            int col = __shfl(mycol, idx);
            float val = __shfl(ev.y, idx);
            const float4 vv = *reinterpret_cast<const float4*>(
                v + (size_t)col * D_IN + l32 * 4);
            acc.x = fmaf(val, vv.x, acc.x);
            acc.y = fmaf(val, vv.y, acc.y);
            acc.z = fmaf(val, vv.z, acc.z);
            acc.w = fmaf(val, vv.w, acc.w);
        }
    }
    acc.x += __shfl_down(acc.x, 32);
    acc.y += __shfl_down(acc.y, 32);
    acc.z += __shfl_down(acc.z, 32);
    acc.w += __shfl_down(acc.w, 32);
    if (half == 0) {
        const float eps = *epsp;
        const float4 vs = *reinterpret_cast<const float4*>(
            v + (size_t)wid * D_IN + l32 * 4);
        u32 a0 = (u32)f2b(fmaf(eps, vs.x, acc.x)) |
                 ((u32)f2b(fmaf(eps, vs.y, acc.y)) << 16);
        u32 a1 = (u32)f2b(fmaf(eps, vs.z, acc.z)) |
                 ((u32)f2b(fmaf(eps, vs.w, acc.w)) << 16);
        *reinterpret_cast<uint2*>(x + (size_t)wid * D_IN + l32 * 4) =
            make_uint2(a0, a1);
    }
}

// ---------------------------------------------------------------------------
// 5/6) MFMA GEMM: C[M][NSTR] (bf16) = A[M][KT] (bf16) @ Bt[n][k] (bf16)
//      BM=64, BN=128, BK=128, 4 waves, XOR-swizzled LDS.
//      Stats: LDS cross-wave reduce -> NON-ATOMIC per-block partials
//      (G12: same-address fp32 atomic chains measured ~190cyc each — a
//       3128-deep chain was the 239us convoy in round 9).
//      BNA=true: A-staging applies relu(a*f.x+f.y) with f cached in LDS.
// ---------------------------------------------------------------------------
template <int KT, int NSTR, bool BNA>
__global__ __launch_bounds__(256) void gemm_mf(
    const u16* __restrict__ A, const u16* __restrict__ Bt,
    const float2* __restrict__ fA, u16* __restrict__ C,
    float* __restrict__ part1, float* __restrict__ part2, int M)
{
    __shared__ __align__(16) u16 As[64 * 128];    // 16 KB, swizzled
    __shared__ __align__(16) u16 Bs[128 * 128];   // 32 KB, swizzled
    __shared__ float2 fs[256];                    // BN factors cache (2 KB)

    const int tid = threadIdx.x;
    const int bm = blockIdx.x * 64;
    const int bn0 = blockIdx.y * 128;
    const int l = tid & 63;
    const int wv = tid >> 6;
    const int wm = wv * 16;                // wave's 16-row band
    char* AsB = reinterpret_cast<char*>(As);
    char* BsB = reinterpret_cast<char*>(Bs);

    if (BNA) fs[tid] = fA[tid];            // KT==256 when BNA

    f32x4 acc[8];
#pragma unroll
    for (int t = 0; t < 8; ++t) acc[t] = (f32x4){0.f, 0.f, 0.f, 0.f};

    for (int kk = 0; kk < KT; kk += 128) {
        __syncthreads();                   // fs ready / previous pass done
        // ---- stage A tile (64 x 128 bf16), swizzled ----
#pragma unroll
        for (int i = 0; i < 4; ++i) {
            int c = tid + i * 256;
            int row = c >> 4, slot = c & 15;
            uint4 val = make_uint4(0u, 0u, 0u, 0u);
            if (bm + row < M)
                val = *reinterpret_cast<const uint4*>(
                    A + (size_t)(bm + row) * KT + kk + slot * 8);
            if (BNA) {
                u16* hp = reinterpret_cast<u16*>(&val);
#pragma unroll
                for (int j = 0; j < 8; ++j) {
                    float2 f = fs[kk + slot * 8 + j];
                    hp[j] = f2b(fmaxf(fmaf(b2f(hp[j]), f.x, f.y), 0.f));
                }
            }
            *reinterpret_cast<uint4*>(
                AsB + ((row * 256 + slot * 16) ^ ((row & 7) << 4))) = val;
        }
        // ---- stage B tile (128 x 128 bf16), swizzled ----
#pragma unroll
        for (int i = 0; i < 8; ++i) {
            int c = tid + i * 256;
            int n = c >> 4, slot = c & 15;
            uint4 val = *reinterpret_cast<const uint4*>(
                Bt + (size_t)(bn0 + n) * KT + kk + slot * 8);
            *reinterpret_cast<uint4*>(
                BsB + ((n * 256 + slot * 16) ^ ((n & 7) << 4))) = val;
        }
        __syncthreads();
        // ---- MFMA: wave computes 16 rows x 128 cols ----
#pragma unroll
        for (int s = 0; s < 4; ++s) {
            int ka = (s * 32 + (l >> 4) * 8) * 2;      // k byte offset in row
            int arow = wm + (l & 15);
            bf16x8 af = *reinterpret_cast<bf16x8*>(
                AsB + ((arow * 256 + ka) ^ ((l & 7) << 4)));
#pragma unroll
            for (int t = 0; t < 8; ++t) {
                int brow = t * 16 + (l & 15);
                bf16x8 bfr = *reinterpret_cast<bf16x8*>(
                    BsB + ((brow * 256 + ka) ^ ((l & 7) << 4)));
                acc[t] = __builtin_amdgcn_mfma_f32_16x16x32_bf16(
                    af, bfr, acc[t], 0, 0, 0);
            }
        }
    }

    __syncthreads();   // [A] all MFMA LDS reads done; As/Bs reusable

    // ---- stats partials -> Bs (as float); padded rows contribute 0 ----
    float* bsF = reinterpret_cast<float*>(Bs);
#pragma unroll
    for (int t = 0; t < 8; ++t) {
        float s = acc[t][0] + acc[t][1] + acc[t][2] + acc[t][3];
        float q = acc[t][0] * acc[t][0] + acc[t][1] * acc[t][1]
                + acc[t][2] * acc[t][2] + acc[t][3] * acc[t][3];
        s += __shfl_down(s, 32);  q += __shfl_down(q, 32);
        s += __shfl_down(s, 16);  q += __shfl_down(q, 16);
        if (l < 16) {
            int c = t * 16 + l;
            bsF[wv * 128 + c]       = s;
            bsF[512 + wv * 128 + c] = q;
        }
    }

    // ---- C restage: acc -> As (bf16, swizzled) ----
#pragma unroll
    for (int t = 0; t < 8; ++t) {
#pragma unroll
        for (int r = 0; r < 4; ++r) {
            int row = wm + (l >> 4) * 4 + r;
            int col = t * 16 + (l & 15);
            *reinterpret_cast<u16*>(
                AsB + ((row * 256 + col * 2) ^ ((row & 7) << 4))) =
                f2b(acc[t][r]);
        }
    }
    __syncthreads();   // [B]

    // ---- C store (coalesced 16B) ----
#pragma unroll
    for (int i = 0; i < 4; ++i) {
        int c = tid + i * 256;
        int row = c >> 4, slot = c & 15;
        if (bm + row < M) {
            uint4 val = *reinterpret_cast<uint4*>(
                AsB + ((row * 256 + slot * 16) ^ ((row & 7) << 4)));
            *reinterpret_cast<uint4*>(
                C + (size_t)(bm + row) * NSTR + bn0 + slot * 8) = val;
        }
    }
    // ---- per-block stats partials, coalesced, NO atomics ----
    if (tid < 128) {
        float s = bsF[tid] + bsF[128 + tid] + bsF[256 + tid] + bsF[384 + tid];
        float q = bsF[512 + tid] + bsF[640 + tid]
                + bsF[768 + tid] + bsF[896 + tid];
        part1[(size_t)blockIdx.x * NSTR + bn0 + tid] = s;
        part2[(size_t)blockIdx.x * NSTR + bn0 + tid] = q;
    }
}

// ---------------------------------------------------------------------------
// 6b) column reduce of per-block partials (16-deep atomic chains only)
// ---------------------------------------------------------------------------
__global__ void colreduce(const float* __restrict__ part1,
                          const float* __restrict__ part2,
                          float* __restrict__ sum, float* __restrict__ sq,
                          int NBX, int C)
{
    int col = threadIdx.x;                 // blockDim == C
    float s = 0.f, q = 0.f;
    for (int bx = blockIdx.x; bx < NBX; bx += gridDim.x) {
        s += part1[(size_t)bx * C + col];  // coalesced across threads
        q += part2[(size_t)bx * C + col];
    }
    atomicAdd(&sum[col], s);
    atomicAdd(&sq[col], q);
}

// ---------------------------------------------------------------------------
// 7) BN factors: s = g*rsqrt(var+eps); t = be - mean*s  (linear bias cancels)
// ---------------------------------------------------------------------------
__global__ void bnfactors(const float* __restrict__ sum, const float* __restrict__ sq,
                          const float* __restrict__ g, const float* __restrict__ be,
                          float2* __restrict__ f, int C, int M)
{
    int c = threadIdx.x;
    if (c < C) {
        float inv = 1.f / (float)M;
        float mean = sum[c] * inv;
        float var = fmaxf(sq[c] * inv - mean * mean, 0.f);
        float s = g[c] * rsqrtf(var + BN_EPS);
        f[c] = make_float2(s, be[c] - mean * s);
    }
}

// ---------------------------------------------------------------------------
// 8) final elementwise: out = relu(y2*s2 + t2), y2 bf16 -> out fp32
// ---------------------------------------------------------------------------
__global__ __launch_bounds__(256) void bnrelu_out(
    const u16* __restrict__ y2, const float2* __restrict__ f2,
    float* __restrict__ out, int total8)
{
    int i = blockIdx.x * 256 + threadIdx.x;
    if (i >= total8) return;
    uint4 val = *reinterpret_cast<const uint4*>(y2 + (size_t)i * 8);
    const u16* hp = reinterpret_cast<const u16*>(&val);
    int c = (i & 15) * 8;                  // D_OUT=128 -> 16 chunks/row
    float r[8];
#pragma unroll
    for (int j = 0; j < 8; ++j) {
        float2 f = f2[c + j];
        r[j] = fmaxf(fmaf(b2f(hp[j]), f.x, f.y), 0.f);
    }
    *reinterpret_cast<float4*>(out + (size_t)i * 8) =
        make_float4(r[0], r[1], r[2], r[3]);
    *reinterpret_cast<float4*>(out + (size_t)i * 8 + 4) =
        make_float4(r[4], r[5], r[6], r[7]);
}

// ---------------------------------------------------------------------------
extern "C" void kernel_launch(void* const* d_in, const int* in_sizes, int n_in,
                              void* d_out, int out_size, void* d_ws, size_t ws_size,
                              hipStream_t stream)
{
    const float* v     = (const float*)d_in[0];
    const int*   erows = (const int*)d_in[1];
    const int*   ecols = (const int*)d_in[2];
    const float* evals = (const float*)d_in[3];
    const float* w1    = (const float*)d_in[4];
    // b1 = d_in[5], b2 = d_in[9]: linear bias cancels exactly inside BatchNorm.
    const float* g1    = (const float*)d_in[6];
    const float* be1   = (const float*)d_in[7];
    const float* w2    = (const float*)d_in[8];
    const float* g2    = (const float*)d_in[10];
    const float* be2   = (const float*)d_in[11];
    const float* eps   = (const float*)d_in[12];

    const int M = in_sizes[0] / D_IN;   // 50000
    const int E = in_sizes[3];          // 800000
    const int NB = (M + 255) / 256;     // 196 chunks
    const int NBX = (M + 63) / 64;      // 782 gemm row-blocks

    u16* xb  = (u16*)d_ws;                           // M*128 bf16
    u16* y1b = xb + (size_t)M * D_IN;                // M*256 bf16
    u16* w1t = y1b + (size_t)M * D_HID;              // 32768
    u16* w2t = w1t + 32768;                          // 32768
    int* rowstart = (int*)(w2t + 32768);             // N+1
    int* cursor   = rowstart + M + 2;
    int* cnthist  = cursor + M;
    int* bsum     = cnthist + M;                     // 256
    int* coff     = bsum + 256;                      // 256
    size_t ecv_ofs = ((size_t)(coff + 256 - (int*)d_ws) + 1) & ~(size_t)1;
    float2* ecv = (float2*)((float*)d_ws + ecv_ofs); // E float2
    float* st   = (float*)(ecv + E);
    float* sum1 = st;
    float* sq1  = sum1 + D_HID;
    float* sum2 = sq1 + D_HID;
    float* sq2  = sum2 + D_OUT;
    float2* f1  = (float2*)(sq2 + D_OUT);            // 256 float2
    float2* f2  = f1 + D_HID;                        // 128 float2
    float* pA1  = (float*)(f2 + D_OUT);              // NBX*256 (gemm1 sum)
    float* pA2  = pA1 + (size_t)NBX * 256;           // NBX*256 (gemm1 sq)
    float* pB1  = pA2 + (size_t)NBX * 256;           // NBX*128 (gemm2 sum)
    float* pB2  = pB1 + (size_t)NBX * 128;           // NBX*128 (gemm2 sq)
    u16* y2b    = xb;                                // alias: x dead after GEMM1
    float* outp = (float*)d_out;

    hipMemsetAsync(cnthist, 0, (size_t)M * sizeof(int), stream);
    hipMemsetAsync(st, 0, (size_t)(2 * D_HID + 2 * D_OUT) * sizeof(float), stream);

    cvt_w<<<256, 256, 0, stream>>>(w1, w2, w1t, w2t);
    edge_hist<<<(E + 255) / 256, 256, 0, stream>>>(erows, cnthist, E);
    chunk_sums<<<NB, 256, 0, stream>>>(cnthist, bsum, M);
    scan_chunks<<<1, 256, 0, stream>>>(bsum, coff, NB);
    scan_write<<<NB, 256, 0, stream>>>(cnthist, coff, rowstart, cursor, M);
    edge_scatter<<<(E + 255) / 256, 256, 0, stream>>>(erows, ecols, evals, cursor, ecv, E);
    spmm_rows<<<(M * 64 + 255) / 256, 256, 0, stream>>>(v, rowstart, ecv, eps, xb, M);

    dim3 grid1(NBX, 2);
    gemm_mf<128, 256, false><<<grid1, 256, 0, stream>>>(
        xb, w1t, nullptr, y1b, pA1, pA2, M);
    colreduce<<<16, 256, 0, stream>>>(pA1, pA2, sum1, sq1, NBX, 256);
    bnfactors<<<1, D_HID, 0, stream>>>(sum1, sq1, g1, be1, f1, D_HID, M);

    dim3 grid2(NBX, 1);
    gemm_mf<256, 128, true><<<grid2, 256, 0, stream>>>(
        y1b, w2t, f1, y2b, pB1, pB2, M);
    colreduce<<<16, 128, 0, stream>>>(pB1, pB2, sum2, sq2, NBX, 128);
    bnfactors<<<1, D_OUT, 0, stream>>>(sum2, sq2, g2, be2, f2, D_OUT, M);

    bnrelu_out<<<(M * D_OUT / 8 + 255) / 256, 256, 0, stream>>>(
        y2b, f2, outp, M * D_OUT / 8);
}

// Round 12
// 319.424 us; speedup vs baseline: 2.0975x; 1.0669x over previous
//
#include <hip/hip_runtime.h>

#define D_IN 128
#define D_HID 256
#define D_OUT 128
#define BN_EPS 1e-5f

typedef unsigned short u16;
typedef unsigned int u32;
typedef __attribute__((ext_vector_type(8))) short bf16x8;
typedef __attribute__((ext_vector_type(4))) float f32x4;

__device__ __forceinline__ u16 f2b(float f) {   // fp32 -> bf16 RNE
    u32 u = __float_as_uint(f);
    return (u16)((u + 0x7FFFu + ((u >> 16) & 1u)) >> 16);
}
__device__ __forceinline__ float b2f(u16 h) {
    return __uint_as_float(((u32)h) << 16);
}

// ---------------------------------------------------------------------------
// 0a) convert + transpose weights to bf16 [n][k] (one-time, tiny)
// ---------------------------------------------------------------------------
__global__ __launch_bounds__(256) void cvt_w(
    const float* __restrict__ w1, const float* __restrict__ w2,
    u16* __restrict__ w1t, u16* __restrict__ w2t)
{
    int i = blockIdx.x * 256 + threadIdx.x;
    if (i < 32768) {                       // w1t[n][k], n<256,k<128 <- w1[k][n]
        int n = i >> 7, k = i & 127;
        w1t[i] = f2b(w1[k * 256 + n]);
    } else {                               // w2t[n][k], n<128,k<256 <- w2[k][n]
        int j = i - 32768;
        int n = j >> 8, k = j & 255;
        w2t[j] = f2b(w2[k * 128 + n]);
    }
}

// ---------------------------------------------------------------------------
// 0b) convert v to bf16 (halves spmm gather bytes; vb ~12.8MB fits L2 better)
// ---------------------------------------------------------------------------
__global__ __launch_bounds__(256) void cvt_v(
    const float* __restrict__ v, u16* __restrict__ vb, int total8)
{
    int i = blockIdx.x * 256 + threadIdx.x;
    if (i >= total8) return;
    float4 a = *reinterpret_cast<const float4*>(v + (size_t)i * 8);
    float4 b = *reinterpret_cast<const float4*>(v + (size_t)i * 8 + 4);
    u16 h[8] = {f2b(a.x), f2b(a.y), f2b(a.z), f2b(a.w),
                f2b(b.x), f2b(b.y), f2b(b.z), f2b(b.w)};
    *reinterpret_cast<uint4*>(vb + (size_t)i * 8) =
        *reinterpret_cast<uint4*>(h);
}

// ---------------------------------------------------------------------------
// 1) histogram
// ---------------------------------------------------------------------------
__global__ __launch_bounds__(256) void edge_hist(
    const int* __restrict__ rows, int* __restrict__ cnt, int E)
{
    int e = blockIdx.x * 256 + threadIdx.x;
    if (e < E) atomicAdd(&cnt[rows[e]], 1);
}

// ---------------------------------------------------------------------------
// 2a/2b/2c) device-wide exclusive scan (3 phases)
// ---------------------------------------------------------------------------
__global__ __launch_bounds__(256) void chunk_sums(
    const int* __restrict__ cnt, int* __restrict__ bsum, int N)
{
    __shared__ int red[256];
    const int t = threadIdx.x;
    const int i = blockIdx.x * 256 + t;
    red[t] = (i < N) ? cnt[i] : 0;
    __syncthreads();
#pragma unroll
    for (int off = 128; off > 0; off >>= 1) {
        if (t < off) red[t] += red[t + off];
        __syncthreads();
    }
    if (t == 0) bsum[blockIdx.x] = red[0];
}

__global__ __launch_bounds__(256) void scan_chunks(
    const int* __restrict__ bsum, int* __restrict__ coff, int NB)
{
    __shared__ int s[256];
    const int t = threadIdx.x;
    int c = (t < NB) ? bsum[t] : 0;
    s[t] = c;
    __syncthreads();
#pragma unroll
    for (int off = 1; off < 256; off <<= 1) {
        int x = (t >= off) ? s[t - off] : 0;
        __syncthreads();
        s[t] += x;
        __syncthreads();
    }
    coff[t] = s[t] - c;
}

__global__ __launch_bounds__(256) void scan_write(
    const int* __restrict__ cnt, const int* __restrict__ coff,
    int* __restrict__ rowstart, int* __restrict__ cursor, int N)
{
    __shared__ int s[256];
    const int t = threadIdx.x;
    const int i = blockIdx.x * 256 + t;
    int c = (i < N) ? cnt[i] : 0;
    s[t] = c;
    __syncthreads();
#pragma unroll
    for (int off = 1; off < 256; off <<= 1) {
        int x = (t >= off) ? s[t - off] : 0;
        __syncthreads();
        s[t] += x;
        __syncthreads();
    }
    int pos = coff[blockIdx.x] + s[t] - c;
    if (i < N) {
        rowstart[i] = pos;
        cursor[i] = pos;
    } else if (i == N) {
        rowstart[N] = pos;
    }
}

// ---------------------------------------------------------------------------
// 3) bucket-scatter edges
// ---------------------------------------------------------------------------
__global__ __launch_bounds__(256) void edge_scatter(
    const int* __restrict__ rows, const int* __restrict__ cols,
    const float* __restrict__ vals, int* __restrict__ cursor,
    float2* __restrict__ ecv, int E)
{
    int e = blockIdx.x * 256 + threadIdx.x;
    if (e >= E) return;
    int r = rows[e];
    int pos = atomicAdd(&cursor[r], 1);
    ecv[pos] = make_float2(__int_as_float(cols[e]), vals[e]);
}

// ---------------------------------------------------------------------------
// 4) gather-aggregate: one wave/row, 4 edges in flight (16-lane quarters).
//    bf16 gather (256B/edge), fp32 accumulate; writes x as bf16.
// ---------------------------------------------------------------------------
__global__ __launch_bounds__(256) void spmm_rows(
    const u16* __restrict__ vb, const int* __restrict__ rowstart,
    const float2* __restrict__ ecv, const float* __restrict__ epsp,
    u16* __restrict__ x, int N)
{
    int wid = (blockIdx.x * 256 + threadIdx.x) >> 6;
    if (wid >= N) return;
    const int lane = threadIdx.x & 63;
    const int quarter = lane >> 4;      // which edge of the 4-group
    const int l16 = lane & 15;          // feat group: 8 bf16
    const int s = rowstart[wid], e = rowstart[wid + 1];
    float acc[8] = {};

    for (int base = s; base < e; base += 64) {
        int n = min(64, e - base);
        // pad lanes get val=0, col=0 -> harmless vb[0] read, adds 0
        float2 ev = make_float2(0.f, 0.f);
        if (base + lane < e) ev = ecv[base + lane];
        int mycol = __float_as_int(ev.x);
        int quads = (n + 3) >> 2;
        for (int k = 0; k < quads; ++k) {
            int idx = 4 * k + quarter;
            int col = __shfl(mycol, idx);
            float val = __shfl(ev.y, idx);
            uint4 vv = *reinterpret_cast<const uint4*>(
                vb + (size_t)col * D_IN + l16 * 8);
            const u16* hp = reinterpret_cast<const u16*>(&vv);
#pragma unroll
            for (int j = 0; j < 8; ++j)
                acc[j] = fmaf(val, b2f(hp[j]), acc[j]);
        }
    }
    // combine quarters (same feats, different edges)
#pragma unroll
    for (int j = 0; j < 8; ++j) acc[j] += __shfl_down(acc[j], 32);
#pragma unroll
    for (int j = 0; j < 8; ++j) acc[j] += __shfl_down(acc[j], 16);
    if (quarter == 0) {
        const float eps = *epsp;
        uint4 vs = *reinterpret_cast<const uint4*>(
            vb + (size_t)wid * D_IN + l16 * 8);
        const u16* vp = reinterpret_cast<const u16*>(&vs);
        u16 o[8];
#pragma unroll
        for (int j = 0; j < 8; ++j)
            o[j] = f2b(fmaf(eps, b2f(vp[j]), acc[j]));
        *reinterpret_cast<uint4*>(x + (size_t)wid * D_IN + l16 * 8) =
            *reinterpret_cast<uint4*>(o);
    }
}

// ---------------------------------------------------------------------------
// 5/6) MFMA GEMM: C[M][NSTR] (bf16) = A[M][KT] (bf16) @ Bt[n][k] (bf16)
//      BM=64, BN=128, BK=128, 4 waves, XOR-swizzled LDS.
//      Stats: LDS cross-wave reduce -> NON-ATOMIC per-block partials
//      (G12: same-address fp32 atomic chains ~190cyc each; the 3128-deep
//       chain was round 9's 239us convoy — confirmed fixed in round 11).
//      BNA=true: A-staging applies relu(a*f.x+f.y) with f cached in LDS.
// ---------------------------------------------------------------------------
template <int KT, int NSTR, bool BNA>
__global__ __launch_bounds__(256) void gemm_mf(
    const u16* __restrict__ A, const u16* __restrict__ Bt,
    const float2* __restrict__ fA, u16* __restrict__ C,
    float* __restrict__ part1, float* __restrict__ part2, int M)
{
    __shared__ __align__(16) u16 As[64 * 128];    // 16 KB, swizzled
    __shared__ __align__(16) u16 Bs[128 * 128];   // 32 KB, swizzled
    __shared__ float2 fs[256];                    // BN factors cache (2 KB)

    const int tid = threadIdx.x;
    const int bm = blockIdx.x * 64;
    const int bn0 = blockIdx.y * 128;
    const int l = tid & 63;
    const int wv = tid >> 6;
    const int wm = wv * 16;                // wave's 16-row band
    char* AsB = reinterpret_cast<char*>(As);
    char* BsB = reinterpret_cast<char*>(Bs);

    if (BNA) fs[tid] = fA[tid];            // KT==256 when BNA

    f32x4 acc[8];
#pragma unroll
    for (int t = 0; t < 8; ++t) acc[t] = (f32x4){0.f, 0.f, 0.f, 0.f};

    for (int kk = 0; kk < KT; kk += 128) {
        __syncthreads();                   // fs ready / previous pass done
        // ---- stage A tile (64 x 128 bf16), swizzled ----
#pragma unroll
        for (int i = 0; i < 4; ++i) {
            int c = tid + i * 256;
            int row = c >> 4, slot = c & 15;
            uint4 val = make_uint4(0u, 0u, 0u, 0u);
            if (bm + row < M)
                val = *reinterpret_cast<const uint4*>(
                    A + (size_t)(bm + row) * KT + kk + slot * 8);
            if (BNA) {
                u16* hp = reinterpret_cast<u16*>(&val);
#pragma unroll
                for (int j = 0; j < 8; ++j) {
                    float2 f = fs[kk + slot * 8 + j];
                    hp[j] = f2b(fmaxf(fmaf(b2f(hp[j]), f.x, f.y), 0.f));
                }
            }
            *reinterpret_cast<uint4*>(
                AsB + ((row * 256 + slot * 16) ^ ((row & 7) << 4))) = val;
        }
        // ---- stage B tile (128 x 128 bf16), swizzled ----
#pragma unroll
        for (int i = 0; i < 8; ++i) {
            int c = tid + i * 256;
            int n = c >> 4, slot = c & 15;
            uint4 val = *reinterpret_cast<const uint4*>(
                Bt + (size_t)(bn0 + n) * KT + kk + slot * 8);
            *reinterpret_cast<uint4*>(
                BsB + ((n * 256 + slot * 16) ^ ((n & 7) << 4))) = val;
        }
        __syncthreads();
        // ---- MFMA: wave computes 16 rows x 128 cols ----
#pragma unroll
        for (int s = 0; s < 4; ++s) {
            int ka = (s * 32 + (l >> 4) * 8) * 2;      // k byte offset in row
            int arow = wm + (l & 15);
            bf16x8 af = *reinterpret_cast<bf16x8*>(
                AsB + ((arow * 256 + ka) ^ ((l & 7) << 4)));
#pragma unroll
            for (int t = 0; t < 8; ++t) {
                int brow = t * 16 + (l & 15);
                bf16x8 bfr = *reinterpret_cast<bf16x8*>(
                    BsB + ((brow * 256 + ka) ^ ((l & 7) << 4)));
                acc[t] = __builtin_amdgcn_mfma_f32_16x16x32_bf16(
                    af, bfr, acc[t], 0, 0, 0);
            }
        }
    }

    __syncthreads();   // [A] all MFMA LDS reads done; As/Bs reusable

    // ---- stats partials -> Bs (as float); padded rows contribute 0 ----
    float* bsF = reinterpret_cast<float*>(Bs);
#pragma unroll
    for (int t = 0; t < 8; ++t) {
        float s = acc[t][0] + acc[t][1] + acc[t][2] + acc[t][3];
        float q = acc[t][0] * acc[t][0] + acc[t][1] * acc[t][1]
                + acc[t][2] * acc[t][2] + acc[t][3] * acc[t][3];
        s += __shfl_down(s, 32);  q += __shfl_down(q, 32);
        s += __shfl_down(s, 16);  q += __shfl_down(q, 16);
        if (l < 16) {
            int c = t * 16 + l;
            bsF[wv * 128 + c]       = s;
            bsF[512 + wv * 128 + c] = q;
        }
    }

    // ---- C restage: acc -> As (bf16, swizzled) ----
#pragma unroll
    for (int t = 0; t < 8; ++t) {
#pragma unroll
        for (int r = 0; r < 4; ++r) {
            int row = wm + (l >> 4) * 4 + r;
            int col = t * 16 + (l & 15);
            *reinterpret_cast<u16*>(
                AsB + ((row * 256 + col * 2) ^ ((row & 7) << 4))) =
                f2b(acc[t][r]);
        }
    }
    __syncthreads();   // [B]

    // ---- C store (coalesced 16B) ----
#pragma unroll
    for (int i = 0; i < 4; ++i) {
        int c = tid + i * 256;
        int row = c >> 4, slot = c & 15;
        if (bm + row < M) {
            uint4 val = *reinterpret_cast<uint4*>(
                AsB + ((row * 256 + slot * 16) ^ ((row & 7) << 4)));
            *reinterpret_cast<uint4*>(
                C + (size_t)(bm + row) * NSTR + bn0 + slot * 8) = val;
        }
    }
    // ---- per-block stats partials, coalesced, NO atomics ----
    if (tid < 128) {
        float s = bsF[tid] + bsF[128 + tid] + bsF[256 + tid] + bsF[384 + tid];
        float q = bsF[512 + tid] + bsF[640 + tid]
                + bsF[768 + tid] + bsF[896 + tid];
        part1[(size_t)blockIdx.x * NSTR + bn0 + tid] = s;
        part2[(size_t)blockIdx.x * NSTR + bn0 + tid] = q;
    }
}

// ---------------------------------------------------------------------------
// 6b) column reduce of per-block partials (16-deep atomic chains only)
// ---------------------------------------------------------------------------
__global__ void colreduce(const float* __restrict__ part1,
                          const float* __restrict__ part2,
                          float* __restrict__ sum, float* __restrict__ sq,
                          int NBX, int C)
{
    int col = threadIdx.x;                 // blockDim == C
    float s = 0.f, q = 0.f;
    for (int bx = blockIdx.x; bx < NBX; bx += gridDim.x) {
        s += part1[(size_t)bx * C + col];  // coalesced across threads
        q += part2[(size_t)bx * C + col];
    }
    atomicAdd(&sum[col], s);
    atomicAdd(&sq[col], q);
}

// ---------------------------------------------------------------------------
// 7) BN factors: s = g*rsqrt(var+eps); t = be - mean*s  (linear bias cancels)
// ---------------------------------------------------------------------------
__global__ void bnfactors(const float* __restrict__ sum, const float* __restrict__ sq,
                          const float* __restrict__ g, const float* __restrict__ be,
                          float2* __restrict__ f, int C, int M)
{
    int c = threadIdx.x;
    if (c < C) {
        float inv = 1.f / (float)M;
        float mean = sum[c] * inv;
        float var = fmaxf(sq[c] * inv - mean * mean, 0.f);
        float s = g[c] * rsqrtf(var + BN_EPS);
        f[c] = make_float2(s, be[c] - mean * s);
    }
}

// ---------------------------------------------------------------------------
// 8) final elementwise: out = relu(y2*s2 + t2), y2 bf16 -> out fp32
// ---------------------------------------------------------------------------
__global__ __launch_bounds__(256) void bnrelu_out(
    const u16* __restrict__ y2, const float2* __restrict__ f2,
    float* __restrict__ out, int total8)
{
    int i = blockIdx.x * 256 + threadIdx.x;
    if (i >= total8) return;
    uint4 val = *reinterpret_cast<const uint4*>(y2 + (size_t)i * 8);
    const u16* hp = reinterpret_cast<const u16*>(&val);
    int c = (i & 15) * 8;                  // D_OUT=128 -> 16 chunks/row
    float r[8];
#pragma unroll
    for (int j = 0; j < 8; ++j) {
        float2 f = f2[c + j];
        r[j] = fmaxf(fmaf(b2f(hp[j]), f.x, f.y), 0.f);
    }
    *reinterpret_cast<float4*>(out + (size_t)i * 8) =
        make_float4(r[0], r[1], r[2], r[3]);
    *reinterpret_cast<float4*>(out + (size_t)i * 8 + 4) =
        make_float4(r[4], r[5], r[6], r[7]);
}

// ---------------------------------------------------------------------------
extern "C" void kernel_launch(void* const* d_in, const int* in_sizes, int n_in,
                              void* d_out, int out_size, void* d_ws, size_t ws_size,
                              hipStream_t stream)
{
    const float* v     = (const float*)d_in[0];
    const int*   erows = (const int*)d_in[1];
    const int*   ecols = (const int*)d_in[2];
    const float* evals = (const float*)d_in[3];
    const float* w1    = (const float*)d_in[4];
    // b1 = d_in[5], b2 = d_in[9]: linear bias cancels exactly inside BatchNorm.
    const float* g1    = (const float*)d_in[6];
    const float* be1   = (const float*)d_in[7];
    const float* w2    = (const float*)d_in[8];
    const float* g2    = (const float*)d_in[10];
    const float* be2   = (const float*)d_in[11];
    const float* eps   = (const float*)d_in[12];

    const int M = in_sizes[0] / D_IN;   // 50000
    const int E = in_sizes[3];          // 800000
    const int NB = (M + 255) / 256;     // 196 chunks
    const int NBX = (M + 63) / 64;      // 782 gemm row-blocks

    u16* xb  = (u16*)d_ws;                           // M*128 bf16
    u16* y1b = xb + (size_t)M * D_IN;                // M*256 bf16
    u16* vb  = y1b + (size_t)M * D_HID;              // M*128 bf16 (v gather copy)
    u16* w1t = vb + (size_t)M * D_IN;                // 32768
    u16* w2t = w1t + 32768;                          // 32768
    int* rowstart = (int*)(w2t + 32768);             // N+1
    int* cursor   = rowstart + M + 2;
    int* cnthist  = cursor + M;
    int* bsum     = cnthist + M;                     // 256
    int* coff     = bsum + 256;                      // 256
    size_t ecv_ofs = ((size_t)(coff + 256 - (int*)d_ws) + 1) & ~(size_t)1;
    float2* ecv = (float2*)((float*)d_ws + ecv_ofs); // E float2
    float* st   = (float*)(ecv + E);
    float* sum1 = st;
    float* sq1  = sum1 + D_HID;
    float* sum2 = sq1 + D_HID;
    float* sq2  = sum2 + D_OUT;
    float2* f1  = (float2*)(sq2 + D_OUT);            // 256 float2
    float2* f2  = f1 + D_HID;                        // 128 float2
    float* pA1  = (float*)(f2 + D_OUT);              // NBX*256 (gemm1 sum)
    float* pA2  = pA1 + (size_t)NBX * 256;           // NBX*256 (gemm1 sq)
    float* pB1  = pA2 + (size_t)NBX * 256;           // NBX*128 (gemm2 sum)
    float* pB2  = pB1 + (size_t)NBX * 128;           // NBX*128 (gemm2 sq)
    u16* y2b    = xb;                                // alias: x dead after GEMM1
    float* outp = (float*)d_out;

    hipMemsetAsync(cnthist, 0, (size_t)M * sizeof(int), stream);
    hipMemsetAsync(st, 0, (size_t)(2 * D_HID + 2 * D_OUT) * sizeof(float), stream);

    cvt_w<<<256, 256, 0, stream>>>(w1, w2, w1t, w2t);
    cvt_v<<<(M * D_IN / 8 + 255) / 256, 256, 0, stream>>>(v, vb, M * D_IN / 8);
    edge_hist<<<(E + 255) / 256, 256, 0, stream>>>(erows, cnthist, E);
    chunk_sums<<<NB, 256, 0, stream>>>(cnthist, bsum, M);
    scan_chunks<<<1, 256, 0, stream>>>(bsum, coff, NB);
    scan_write<<<NB, 256, 0, stream>>>(cnthist, coff, rowstart, cursor, M);
    edge_scatter<<<(E + 255) / 256, 256, 0, stream>>>(erows, ecols, evals, cursor, ecv, E);
    spmm_rows<<<(M * 64 + 255) / 256, 256, 0, stream>>>(vb, rowstart, ecv, eps, xb, M);

    dim3 grid1(NBX, 2);
    gemm_mf<128, 256, false><<<grid1, 256, 0, stream>>>(
        xb, w1t, nullptr, y1b, pA1, pA2, M);
    colreduce<<<16, 256, 0, stream>>>(pA1, pA2, sum1, sq1, NBX, 256);
    bnfactors<<<1, D_HID, 0, stream>>>(sum1, sq1, g1, be1, f1, D_HID, M);

    dim3 grid2(NBX, 1);
    gemm_mf<256, 128, true><<<grid2, 256, 0, stream>>>(
        y1b, w2t, f1, y2b, pB1, pB2, M);
    colreduce<<<16, 128, 0, stream>>>(pB1, pB2, sum2, sq2, NBX, 128);
    bnfactors<<<1, D_OUT, 0, stream>>>(sum2, sq2, g2, be2, f2, D_OUT, M);

    bnrelu_out<<<(M * D_OUT / 8 + 255) / 256, 256, 0, stream>>>(
        y2b, f2, outp, M * D_OUT / 8);
}